// Round 13
// baseline (166.507 us; speedup 1.0000x reference)
//
#include <hip/hip_runtime.h>
#include <hip/hip_fp16.h>
#include <math.h>

#define NQ 14
#define NL 6
#define NT 512
#define BATCH 1024
#define NGATES (NL * NQ)
#define GINIT 0x111   // base correction: a0->c0, a1->c1, a2->c2

// R32 = R26/R31 engine + PING-PONG state buffers (uses the 160KB LDS/CU that
// the in-place engine never touched). Two 64KB buffers per block (128KB):
// each apply reads layout Lam_j from SRC and writes Lam_{j+1} to DST —
// the write-after-read hazard vanishes, so the mid-apply barrier is GONE
// (36 -> 18 barriers) and waves flow read->MFMA->write independently.
// Buffer parity is compile-time (apply index 3L+j; 18 applies = even, so
// measurement reads buf0 exactly as before). Address maps / G-corrections /
// fragment layouts byte-for-byte identical to the verified R31.
// Cost: 1 block/CU (8 waves). R27 measured 1-block at the 2-barrier
// structure = 124us; the bet is 18 fewer barriers + intra-apply decoupling
// beats the lost cross-block overlap. If this regresses, R31 (~146) stands.

typedef _Float16 half8 __attribute__((ext_vector_type(8)));
typedef float f32x16 __attribute__((ext_vector_type(16)));

#define HBUF 32768   // halfs per state buffer (re+im planes)

__device__ constexpr int ring_F(int l, int v) {
    int r = (l % 13) + 1;
    for (int w = 0; w < NQ; ++w) {
        int pc = 13 - w, pt = 13 - ((w + r) % NQ);
        v ^= ((v >> pc) & 1) << pt;
    }
    return v;
}

// correction: keys (a0,a1,a2,a3,p) -> chunk bits 0-2; G bit (3k+t)
__device__ constexpr int gcorr(int G, int a, int p) {
    int keys = (a & 15) | ((p & 1) << 4);
    int c = 0;
    for (int k = 0; k < 5; ++k) if ((keys >> k) & 1) c ^= (G >> (3 * k)) & 7;
    return c;
}
__device__ constexpr int lam0(int a, int p, int G) {
    int chunk = ((a >> 4) & 31) | (((a >> 12) & 1) << 5) | (((a >> 13) & 1) << 6)
              | ((p & 1) << 7) | ((a & 15) << 8);
    chunk ^= gcorr(G, a, p);
    return ((a >> 9) & 7) | (chunk << 3);
}
__device__ constexpr int lam1(int a, int p) {
    int chunk = (a & 15) | (((a >> 13) & 1) << 4) | (((a >> 7) & 1) << 5)
              | (((a >> 8) & 1) << 6) | ((p & 1) << 7) | (((a >> 12) & 1) << 8)
              | (((a >> 9) & 7) << 9);
    chunk ^= (a >> 9) & 7;
    return ((a >> 4) & 7) | (chunk << 3);
}
__device__ constexpr int lam2(int a, int p) {
    int chunk = ((a >> 9) & 31) | (((a >> 3) & 1) << 5) | ((p & 1) << 6)
              | (((a >> 7) & 3) << 7) | (((a >> 4) & 7) << 9);
    chunk ^= (a >> 4) & 7;
    return (a & 7) | (chunk << 3);
}

__device__ constexpr int vrank5(int v0, int v1, int v2, int v3, int v4, int v5) {
    int vs[6] = {v0, v1, v2, v3, v4, v5};
    int basis[5] = {0, 0, 0, 0, 0};
    int r = 0;
    for (int i = 0; i < 6; ++i) {
        int x = vs[i];
        for (int b = 4; b >= 0; --b) {
            if (((x >> b) & 1) == 0) continue;
            if (basis[b]) { x ^= basis[b]; }
            else { basis[b] = x; ++r; break; }
        }
    }
    return r;
}
__device__ constexpr int scat_rank(int L, int G) {
    return vrank5(
        (lam0(ring_F(L, 1), 0, G) >> 1) & 31,
        (lam0(ring_F(L, 2), 0, G) >> 1) & 31,
        (lam0(ring_F(L, 4), 0, G) >> 1) & 31,
        (lam0(ring_F(L, 8), 0, G) >> 1) & 31,
        (lam0(0, 1, G) >> 1) & 31,
        (lam0(ring_F(L, 1 << 11), 0, G) >> 1) & 31);
}
__device__ constexpr int find_g0(int L) {
    if (scat_rank(L, GINIT) == 5) return GINIT;
    for (int s = 0; s < 15; ++s)
        if (scat_rank(L, GINIT ^ (1 << s)) == 5) return GINIT ^ (1 << s);
    for (int s1 = 0; s1 < 15; ++s1)
        for (int s2 = s1 + 1; s2 < 15; ++s2)
            if (scat_rank(L, GINIT ^ (1 << s1) ^ (1 << s2)) == 5)
                return GINIT ^ (1 << s1) ^ (1 << s2);
    int best = GINIT, br = scat_rank(L, GINIT);
    for (int s = 0; s < 15; ++s) {
        int g = GINIT ^ (1 << s);
        int rr = scat_rank(L, g);
        if (rr > br) { best = g; br = rr; }
    }
    return best;
}
__device__ constexpr int gsrc(int L) { return L < 0 ? GINIT : find_g0(L); }

// ---- merged prep: B-fragments straight from weights (gate mats inline) ----
__global__ void prepB_kernel(const float* __restrict__ wts, _Float16* __restrict__ B) {
    int t = blockIdx.x * blockDim.x + threadIdx.x;
    if (t >= NL * 18 * 64) return;
    int lane = t & 63;
    int fi = (t >> 6) % 18;
    int L = t / (18 * 64);
    int a, tt, m;
    if (fi < 8)       { a = 0; tt = fi >> 2;        m = fi & 3; }
    else if (fi < 16) { a = 1; tt = (fi - 8) >> 2;  m = (fi - 8) & 3; }
    else              { a = 2; tt = 0;              m = fi - 16; }
    int h = lane >> 5, c = lane & 31;
    const int nb = (a < 2) ? 5 : 4;
    float gmat[5][8];
    #pragma unroll
    for (int j = 0; j < 5; ++j) {
        if (j < nb) {
            int w = (a == 0) ? (4 - j) : (a == 1) ? (9 - j) : (13 - j);
            int g = L * NQ + w;
            float phi = wts[g*3+0], th = wts[g*3+1], om = wts[g*3+2];
            float cc = cosf(0.5f*th), sn = sinf(0.5f*th);
            float aa = 0.5f*(phi+om), bb = 0.5f*(phi-om);
            float ca = cosf(aa), sa = sinf(aa);
            float cb = cosf(bb), sb = sinf(bb);
            gmat[j][0] = cc*ca;  gmat[j][1] = -cc*sa;   // m00
            gmat[j][2] = -sn*cb; gmat[j][3] = -sn*sb;   // m01
            gmat[j][4] = sn*cb;  gmat[j][5] = -sn*sb;   // m10
            gmat[j][6] = cc*ca;  gmat[j][7] = cc*sa;    // m11
        }
    }
    #pragma unroll
    for (int e = 0; e < 8; ++e) {
        int kc, kp, nc, np;
        if (a < 2) { int kr = 16*m + 8*h + e; int nr = 32*tt + c;
                     kc = kr & 31; kp = kr >> 5; nc = nr & 31; np = nr >> 5; }
        else       { kc = 8*h + e; kp = m; nc = c & 15; np = c >> 4; }
        float gr = 1.f, gi = 0.f;
        #pragma unroll
        for (int j = 0; j < 5; ++j) {
            if (j < nb) {
                const float* ent = &gmat[j][(((nc >> j) & 1) * 2 + ((kc >> j) & 1)) * 2];
                float er = ent[0], ei = ent[1];
                float ngr = gr*er - gi*ei, ngi = gr*ei + gi*er;
                gr = ngr; gi = ngi;
            }
        }
        float v = (kp == np) ? gr : (kp ? -gi : gi);
        B[((L*18 + fi)*64 + lane)*8 + e] = (_Float16)v;
    }
}

// ---- the three applies (R26 maps; ping-pong SRC/DST; 1 barrier each) ----
template<int L>
__device__ __forceinline__ void apply0(_Float16* st, const _Float16* B,
                                       int lane, int l31, int h, int w) {
    constexpr int GR = gsrc(L - 1);
    constexpr int SB = ((3*L) & 1) * HBUF;       // src buffer offset
    constexpr int DB = HBUF - SB;                // dst buffer offset
    half8 Af[2][4];
    const int rb = lam0(w | (l31 << 4) | (h << 12), 0, GR);
    #pragma unroll
    for (int ss = 0; ss < 2; ++ss)
        #pragma unroll
        for (int m = 0; m < 4; ++m)
            Af[ss][m] = *(const half8*)(st + SB + (rb ^ lam0((ss << 3) | ((m & 1) << 13), m >> 1, GR)));
    half8 Bf[8];
    #pragma unroll
    for (int f = 0; f < 8; ++f)
        Bf[f] = *(const half8*)(B + ((L*18 + f)*64 + lane)*8);
    const int wb = lam1(w | (h << 6) | (l31 << 9), 0);
    #pragma unroll
    for (int ss = 0; ss < 2; ++ss)
        #pragma unroll
        for (int t = 0; t < 2; ++t) {
            f32x16 acc;
            #pragma unroll
            for (int j = 0; j < 16; ++j) acc[j] = 0.f;
            #pragma unroll
            for (int m = 0; m < 4; ++m)
                acc = __builtin_amdgcn_mfma_f32_32x32x16_f16(Af[ss][m], Bf[t*4+m], acc, 0, 0, 0);
            #pragma unroll
            for (int q = 0; q < 4; ++q) {
                uint2 wv;
                wv.x = __builtin_bit_cast(unsigned, __builtin_amdgcn_cvt_pkrtz(acc[4*q+0], acc[4*q+1]));
                wv.y = __builtin_bit_cast(unsigned, __builtin_amdgcn_cvt_pkrtz(acc[4*q+2], acc[4*q+3]));
                *(uint2*)(st + DB + (wb ^ lam1((ss << 3) | ((q & 1) << 7) | ((q >> 1) << 8), t))) = wv;
            }
        }
    __syncthreads();
}

template<int L>
__device__ __forceinline__ void apply1(_Float16* st, const _Float16* B,
                                       int lane, int l31, int h, int w) {
    constexpr int SB = ((3*L + 1) & 1) * HBUF;
    constexpr int DB = HBUF - SB;
    half8 Af[2][4];
    const int rb = lam1((l31 & 15) | (h << 7) | (w << 9) | (((l31 >> 4) & 1) << 13), 0);
    #pragma unroll
    for (int ss = 0; ss < 2; ++ss)
        #pragma unroll
        for (int m = 0; m < 4; ++m)
            Af[ss][m] = *(const half8*)(st + SB + (rb ^ lam1((ss << 12) | ((m & 1) << 8), m >> 1)));
    half8 Bf[8];
    #pragma unroll
    for (int f = 0; f < 8; ++f)
        Bf[f] = *(const half8*)(B + ((L*18 + 8 + f)*64 + lane)*8);
    const int wb = lam2((h << 2) | (l31 << 4) | (w << 9), 0);
    #pragma unroll
    for (int ss = 0; ss < 2; ++ss)
        #pragma unroll
        for (int t = 0; t < 2; ++t) {
            f32x16 acc;
            #pragma unroll
            for (int j = 0; j < 16; ++j) acc[j] = 0.f;
            #pragma unroll
            for (int m = 0; m < 4; ++m)
                acc = __builtin_amdgcn_mfma_f32_32x32x16_f16(Af[ss][m], Bf[t*4+m], acc, 0, 0, 0);
            #pragma unroll
            for (int q = 0; q < 4; ++q) {
                uint2 wv;
                wv.x = __builtin_bit_cast(unsigned, __builtin_amdgcn_cvt_pkrtz(acc[4*q+0], acc[4*q+1]));
                wv.y = __builtin_bit_cast(unsigned, __builtin_amdgcn_cvt_pkrtz(acc[4*q+2], acc[4*q+3]));
                *(uint2*)(st + DB + (wb ^ lam2((ss << 12) | ((q & 1) << 3) | ((q >> 1) << 13), t))) = wv;
            }
        }
    __syncthreads();
}

template<int L>
__device__ __forceinline__ void apply2(_Float16* st, const _Float16* B,
                                       int lane, int l31, int h, int w) {
    constexpr int GW = find_g0(L);
    constexpr int SB = ((3*L + 2) & 1) * HBUF;
    constexpr int DB = HBUF - SB;
    half8 Af[4][2];
    const int rb = lam2((h << 3) | (w << 4) | (l31 << 9), 0);
    #pragma unroll
    for (int ss = 0; ss < 4; ++ss)
        #pragma unroll
        for (int m = 0; m < 2; ++m)
            Af[ss][m] = *(const half8*)(st + SB + (rb ^ lam2(ss << 7, m)));
    half8 Bf[2];
    #pragma unroll
    for (int f = 0; f < 2; ++f)
        Bf[f] = *(const half8*)(B + ((L*18 + 16 + f)*64 + lane)*8);
    constexpr int C0 = lam0(ring_F(L, 1), 0, GW);
    constexpr int C1 = lam0(ring_F(L, 2), 0, GW);
    constexpr int C2 = lam0(ring_F(L, 4), 0, GW);
    constexpr int C3 = lam0(ring_F(L, 8), 0, GW);
    constexpr int CP = lam0(0, 1, GW);
    constexpr int CH = lam0(ring_F(L, 1 << 11), 0, GW);
    constexpr int CW0 = lam0(ring_F(L, 1 << 4), 0, GW);
    constexpr int CW1 = lam0(ring_F(L, 1 << 5), 0, GW);
    constexpr int CW2 = lam0(ring_F(L, 1 << 6), 0, GW);
    constexpr int CS0 = lam0(ring_F(L, 1 << 7), 0, GW);
    constexpr int CS1 = lam0(ring_F(L, 1 << 8), 0, GW);
    constexpr int E9  = lam0(ring_F(L, 1 << 9), 0, GW);
    constexpr int E10 = lam0(ring_F(L, 1 << 10), 0, GW);
    constexpr int E12 = lam0(ring_F(L, 1 << 12), 0, GW);
    constexpr int E13 = lam0(ring_F(L, 1 << 13), 0, GW);
    int wb = ((l31 & 1) ? C0 : 0) ^ ((l31 & 2) ? C1 : 0) ^ ((l31 & 4) ? C2 : 0)
           ^ ((l31 & 8) ? C3 : 0) ^ ((l31 & 16) ? CP : 0) ^ (h ? CH : 0)
           ^ ((w & 1) ? CW0 : 0) ^ ((w & 2) ? CW1 : 0) ^ ((w & 4) ? CW2 : 0);
    #pragma unroll
    for (int ss = 0; ss < 4; ++ss) {
        f32x16 acc;
        #pragma unroll
        for (int j = 0; j < 16; ++j) acc[j] = 0.f;
        acc = __builtin_amdgcn_mfma_f32_32x32x16_f16(Af[ss][0], Bf[0], acc, 0, 0, 0);
        acc = __builtin_amdgcn_mfma_f32_32x32x16_f16(Af[ss][1], Bf[1], acc, 0, 0, 0);
        const int ws_ = wb ^ ((ss & 1) ? CS0 : 0) ^ ((ss & 2) ? CS1 : 0);
        #pragma unroll
        for (int r = 0; r < 16; ++r) {
            int wa = ws_ ^ ((r & 1) ? E9 : 0) ^ ((r & 2) ? E10 : 0)
                         ^ ((r & 4) ? E12 : 0) ^ ((r & 8) ? E13 : 0);
            st[DB + wa] = (_Float16)acc[r];
        }
    }
    __syncthreads();
}

template<int L>
__device__ __forceinline__ void do_layer(_Float16* st, const _Float16* B,
                                         int lane, int l31, int h, int w) {
    apply0<L>(st, B, lane, l31, h, w);
    apply1<L>(st, B, lane, l31, h, w);
    apply2<L>(st, B, lane, l31, h, w);
    if constexpr (L < NL - 1) do_layer<L+1>(st, B, lane, l31, h, w);
}

__global__ void __launch_bounds__(NT, 2)
qsim_kernel(const float* __restrict__ x, const _Float16* __restrict__ B,
            float* __restrict__ out)
{
    __shared__ _Float16 st[2 * HBUF];   // 128 KB ping-pong (160 KB LDS/CU)
    const int tid = threadIdx.x;
    const int lane = tid & 63, wid = tid >> 6;
    const int l31 = lane & 31, h = lane >> 5;
    const float* xb = x + blockIdx.x * NQ;

    // ---- product-state init into buf0, Lam0^GINIT, b128 stores ----
    {
        float cr = 1.f, ci = 0.f;
        #pragma unroll
        for (int bb = 0; bb < 3; ++bb) {
            float s, c; __sincosf(0.5f * xb[13 - bb], &s, &c);
            if ((wid >> bb) & 1) { float nr = s*ci, ni = -s*cr; cr = nr; ci = ni; }
            else                 { cr *= c; ci *= c; }
        }
        {
            float s, c; __sincosf(0.5f * xb[10], &s, &c);
            if (h) { float nr = s*ci, ni = -s*cr; cr = nr; ci = ni; }
            else   { cr *= c; ci *= c; }
        }
        #pragma unroll
        for (int bb = 0; bb < 5; ++bb) {
            float s, c; __sincosf(0.5f * xb[9 - bb], &s, &c);
            if ((l31 >> bb) & 1) { float nr = s*ci, ni = -s*cr; cr = nr; ci = ni; }
            else                 { cr *= c; ci *= c; }
        }
        float es[3], ec[3];
        #pragma unroll
        for (int bb = 0; bb < 3; ++bb) __sincosf(0.5f * xb[4 - bb], &es[bb], &ec[bb]);
        float s1, c1, s0, c0;
        __sincosf(0.5f * xb[1], &s1, &c1);
        __sincosf(0.5f * xb[0], &s0, &c0);
        const int ib = lam0(wid | (h << 3) | (l31 << 4), 0, GINIT);
        #pragma unroll
        for (int j2 = 0; j2 < 4; ++j2) {
            float dr = cr, di = ci;
            if (j2 & 1) { float nr = s1*di, ni = -s1*dr; dr = nr; di = ni; }
            else        { dr *= c1; di *= c1; }
            if (j2 >> 1) { float nr = s0*di, ni = -s0*dr; dr = nr; di = ni; }
            else         { dr *= c0; di *= c0; }
            half8 R, I;
            #pragma unroll
            for (int e = 0; e < 8; ++e) {
                float rr = dr, ii = di;
                #pragma unroll
                for (int bb = 0; bb < 3; ++bb) {
                    if ((e >> bb) & 1) { float nr = es[bb]*ii, ni = -es[bb]*rr; rr = nr; ii = ni; }
                    else               { rr *= ec[bb]; ii *= ec[bb]; }
                }
                R[e] = (_Float16)rr; I[e] = (_Float16)ii;
            }
            int da = ((j2 & 1) << 12) | ((j2 >> 1) << 13);
            *(half8*)(st + (ib ^ lam0(da, 0, GINIT))) = R;
            *(half8*)(st + (ib ^ lam0(da, 1, GINIT))) = I;
        }
    }
    __syncthreads();

    do_layer<0>(st, B, lane, l31, h, wid);

    // ---- <Z0>: final state in buf0 (18 applies, even); sign = a13 = m0 ----
    {
        constexpr int G5 = find_g0(NL - 1);
        const int rb = lam0(wid | (l31 << 4) | (h << 12), 0, G5);
        float acc = 0.f;
        #pragma unroll
        for (int ss = 0; ss < 2; ++ss)
            #pragma unroll
            for (int m0 = 0; m0 < 2; ++m0) {
                half8 re = *(const half8*)(st + (rb ^ lam0((ss << 3) | (m0 << 13), 0, G5)));
                half8 im = *(const half8*)(st + (rb ^ lam0((ss << 3) | (m0 << 13), 1, G5)));
                float s = 0.f;
                #pragma unroll
                for (int e = 0; e < 8; ++e) {
                    float r = (float)re[e], iv = (float)im[e];
                    s += r*r + iv*iv;
                }
                acc += m0 ? -s : s;
            }
        #pragma unroll
        for (int off = 32; off > 0; off >>= 1) acc += __shfl_down(acc, off, 64);
        __syncthreads();
        float* f = (float*)st;
        if ((tid & 63) == 0) f[tid >> 6] = acc;
        __syncthreads();
        if (tid == 0) {
            float s = 0.f;
            #pragma unroll
            for (int w = 0; w < NT/64; ++w) s += f[w];
            out[blockIdx.x] = s;
        }
    }
}

extern "C" void kernel_launch(void* const* d_in, const int* in_sizes, int n_in,
                              void* d_out, int out_size, void* d_ws, size_t ws_size,
                              hipStream_t stream) {
    const float* x = (const float*)d_in[0];   // (1024, 14) float32
    const float* w = (const float*)d_in[1];   // (6, 14, 3) float32
    float* out = (float*)d_out;               // (1024,) float32
    _Float16* B = (_Float16*)d_ws;            // 6*18*64*8 halfs of B-frags

    prepB_kernel<<<27, 256, 0, stream>>>(w, B);
    qsim_kernel<<<BATCH, NT, 0, stream>>>(x, B, out);
}

// Round 14
// 145.299 us; speedup vs baseline: 1.1460x; 1.1460x over previous
//
#include <hip/hip_runtime.h>
#include <hip/hip_fp16.h>
#include <math.h>

#define NQ 14
#define NL 6
#define NT 512
#define BATCH 1024
#define NGATES (NL * NQ)
#define GINIT 0x111   // base correction: a0->c0, a1->c1, a2->c2

// R33 = R31/R29 restored (session optimum, verified 3x: steady ~97-100us,
// score ~146): R26's MFMA engine + merged prepB.
// Structural search exhausted — measured triplet:
//   in-place/2-barrier/2-block = 97us (THIS)   [R31]
//   in-place/2-barrier/1-block = 124us          [R27]
//   ping-pong/1-barrier/1-block = 119us         [R32]
// => cross-block overlap (2 resident gangs) dominates barrier count; it and
// 128KB ping-pong are mutually exclusive (state = 64KB irreducible, LDS =
// 160KB/CU). Also rejected with measured mechanisms: occupancy up (R24
// VALU-era null; R28 spill), liveness up (R27 lost 2nd block), setprio
// (R30 cross-block priority inversion, -5%).
// Engine: 16384 complex amps f16 planar in 64KB LDS; per layer 3 fused-gate
// matmuls on mfma_f32_32x32x16_f16 via bank-derived GF(2) layouts
// Lam0/Lam1/Lam2; CNOT ring folded into apply2's write map (per-layer
// G-correction, rank-5 scatter); layer-5 ring folded into measurement sign.

typedef _Float16 half8 __attribute__((ext_vector_type(8)));
typedef float f32x16 __attribute__((ext_vector_type(16)));

__device__ constexpr int ring_F(int l, int v) {
    int r = (l % 13) + 1;
    for (int w = 0; w < NQ; ++w) {
        int pc = 13 - w, pt = 13 - ((w + r) % NQ);
        v ^= ((v >> pc) & 1) << pt;
    }
    return v;
}

// correction: keys (a0,a1,a2,a3,p) -> chunk bits 0-2; G bit (3k+t)
__device__ constexpr int gcorr(int G, int a, int p) {
    int keys = (a & 15) | ((p & 1) << 4);
    int c = 0;
    for (int k = 0; k < 5; ++k) if ((keys >> k) & 1) c ^= (G >> (3 * k)) & 7;
    return c;
}
__device__ constexpr int lam0(int a, int p, int G) {
    int chunk = ((a >> 4) & 31) | (((a >> 12) & 1) << 5) | (((a >> 13) & 1) << 6)
              | ((p & 1) << 7) | ((a & 15) << 8);
    chunk ^= gcorr(G, a, p);
    return ((a >> 9) & 7) | (chunk << 3);
}
__device__ constexpr int lam1(int a, int p) {
    int chunk = (a & 15) | (((a >> 13) & 1) << 4) | (((a >> 7) & 1) << 5)
              | (((a >> 8) & 1) << 6) | ((p & 1) << 7) | (((a >> 12) & 1) << 8)
              | (((a >> 9) & 7) << 9);
    chunk ^= (a >> 9) & 7;
    return ((a >> 4) & 7) | (chunk << 3);
}
__device__ constexpr int lam2(int a, int p) {
    int chunk = ((a >> 9) & 31) | (((a >> 3) & 1) << 5) | ((p & 1) << 6)
              | (((a >> 7) & 3) << 7) | (((a >> 4) & 7) << 9);
    chunk ^= (a >> 4) & 7;
    return (a & 7) | (chunk << 3);
}

__device__ constexpr int vrank5(int v0, int v1, int v2, int v3, int v4, int v5) {
    int vs[6] = {v0, v1, v2, v3, v4, v5};
    int basis[5] = {0, 0, 0, 0, 0};
    int r = 0;
    for (int i = 0; i < 6; ++i) {
        int x = vs[i];
        for (int b = 4; b >= 0; --b) {
            if (((x >> b) & 1) == 0) continue;
            if (basis[b]) { x ^= basis[b]; }
            else { basis[b] = x; ++r; break; }
        }
    }
    return r;
}
__device__ constexpr int scat_rank(int L, int G) {
    return vrank5(
        (lam0(ring_F(L, 1), 0, G) >> 1) & 31,
        (lam0(ring_F(L, 2), 0, G) >> 1) & 31,
        (lam0(ring_F(L, 4), 0, G) >> 1) & 31,
        (lam0(ring_F(L, 8), 0, G) >> 1) & 31,
        (lam0(0, 1, G) >> 1) & 31,
        (lam0(ring_F(L, 1 << 11), 0, G) >> 1) & 31);
}
__device__ constexpr int find_g0(int L) {
    if (scat_rank(L, GINIT) == 5) return GINIT;
    for (int s = 0; s < 15; ++s)
        if (scat_rank(L, GINIT ^ (1 << s)) == 5) return GINIT ^ (1 << s);
    for (int s1 = 0; s1 < 15; ++s1)
        for (int s2 = s1 + 1; s2 < 15; ++s2)
            if (scat_rank(L, GINIT ^ (1 << s1) ^ (1 << s2)) == 5)
                return GINIT ^ (1 << s1) ^ (1 << s2);
    int best = GINIT, br = scat_rank(L, GINIT);
    for (int s = 0; s < 15; ++s) {
        int g = GINIT ^ (1 << s);
        int rr = scat_rank(L, g);
        if (rr > br) { best = g; br = rr; }
    }
    return best;
}
__device__ constexpr int gsrc(int L) { return L < 0 ? GINIT : find_g0(L); }

// ---- merged prep: B-fragments straight from weights (gate mats inline) ----
__global__ void prepB_kernel(const float* __restrict__ wts, _Float16* __restrict__ B) {
    int t = blockIdx.x * blockDim.x + threadIdx.x;
    if (t >= NL * 18 * 64) return;
    int lane = t & 63;
    int fi = (t >> 6) % 18;
    int L = t / (18 * 64);
    int a, tt, m;
    if (fi < 8)       { a = 0; tt = fi >> 2;        m = fi & 3; }
    else if (fi < 16) { a = 1; tt = (fi - 8) >> 2;  m = (fi - 8) & 3; }
    else              { a = 2; tt = 0;              m = fi - 16; }
    int h = lane >> 5, c = lane & 31;
    const int nb = (a < 2) ? 5 : 4;
    float gmat[5][8];
    #pragma unroll
    for (int j = 0; j < 5; ++j) {
        if (j < nb) {
            int w = (a == 0) ? (4 - j) : (a == 1) ? (9 - j) : (13 - j);
            int g = L * NQ + w;
            float phi = wts[g*3+0], th = wts[g*3+1], om = wts[g*3+2];
            float cc = cosf(0.5f*th), sn = sinf(0.5f*th);
            float aa = 0.5f*(phi+om), bb = 0.5f*(phi-om);
            float ca = cosf(aa), sa = sinf(aa);
            float cb = cosf(bb), sb = sinf(bb);
            gmat[j][0] = cc*ca;  gmat[j][1] = -cc*sa;   // m00
            gmat[j][2] = -sn*cb; gmat[j][3] = -sn*sb;   // m01
            gmat[j][4] = sn*cb;  gmat[j][5] = -sn*sb;   // m10
            gmat[j][6] = cc*ca;  gmat[j][7] = cc*sa;    // m11
        }
    }
    #pragma unroll
    for (int e = 0; e < 8; ++e) {
        int kc, kp, nc, np;
        if (a < 2) { int kr = 16*m + 8*h + e; int nr = 32*tt + c;
                     kc = kr & 31; kp = kr >> 5; nc = nr & 31; np = nr >> 5; }
        else       { kc = 8*h + e; kp = m; nc = c & 15; np = c >> 4; }
        float gr = 1.f, gi = 0.f;
        #pragma unroll
        for (int j = 0; j < 5; ++j) {
            if (j < nb) {
                const float* ent = &gmat[j][(((nc >> j) & 1) * 2 + ((kc >> j) & 1)) * 2];
                float er = ent[0], ei = ent[1];
                float ngr = gr*er - gi*ei, ngi = gr*ei + gi*er;
                gr = ngr; gi = ngi;
            }
        }
        float v = (kp == np) ? gr : (kp ? -gi : gi);
        B[((L*18 + fi)*64 + lane)*8 + e] = (_Float16)v;
    }
}

// ---- the three applies (exact R26) ----
template<int L>
__device__ __forceinline__ void apply0(_Float16* st, const _Float16* B,
                                       int lane, int l31, int h, int w) {
    constexpr int GR = gsrc(L - 1);
    half8 Af[2][4];
    const int rb = lam0(w | (l31 << 4) | (h << 12), 0, GR);
    #pragma unroll
    for (int ss = 0; ss < 2; ++ss)
        #pragma unroll
        for (int m = 0; m < 4; ++m)
            Af[ss][m] = *(const half8*)(st + (rb ^ lam0((ss << 3) | ((m & 1) << 13), m >> 1, GR)));
    __syncthreads();
    half8 Bf[8];
    #pragma unroll
    for (int f = 0; f < 8; ++f)
        Bf[f] = *(const half8*)(B + ((L*18 + f)*64 + lane)*8);
    const int wb = lam1(w | (h << 6) | (l31 << 9), 0);
    #pragma unroll
    for (int ss = 0; ss < 2; ++ss)
        #pragma unroll
        for (int t = 0; t < 2; ++t) {
            f32x16 acc;
            #pragma unroll
            for (int j = 0; j < 16; ++j) acc[j] = 0.f;
            #pragma unroll
            for (int m = 0; m < 4; ++m)
                acc = __builtin_amdgcn_mfma_f32_32x32x16_f16(Af[ss][m], Bf[t*4+m], acc, 0, 0, 0);
            #pragma unroll
            for (int q = 0; q < 4; ++q) {
                uint2 wv;
                wv.x = __builtin_bit_cast(unsigned, __builtin_amdgcn_cvt_pkrtz(acc[4*q+0], acc[4*q+1]));
                wv.y = __builtin_bit_cast(unsigned, __builtin_amdgcn_cvt_pkrtz(acc[4*q+2], acc[4*q+3]));
                *(uint2*)(st + (wb ^ lam1((ss << 3) | ((q & 1) << 7) | ((q >> 1) << 8), t))) = wv;
            }
        }
    __syncthreads();
}

template<int L>
__device__ __forceinline__ void apply1(_Float16* st, const _Float16* B,
                                       int lane, int l31, int h, int w) {
    half8 Af[2][4];
    const int rb = lam1((l31 & 15) | (h << 7) | (w << 9) | (((l31 >> 4) & 1) << 13), 0);
    #pragma unroll
    for (int ss = 0; ss < 2; ++ss)
        #pragma unroll
        for (int m = 0; m < 4; ++m)
            Af[ss][m] = *(const half8*)(st + (rb ^ lam1((ss << 12) | ((m & 1) << 8), m >> 1)));
    __syncthreads();
    half8 Bf[8];
    #pragma unroll
    for (int f = 0; f < 8; ++f)
        Bf[f] = *(const half8*)(B + ((L*18 + 8 + f)*64 + lane)*8);
    const int wb = lam2((h << 2) | (l31 << 4) | (w << 9), 0);
    #pragma unroll
    for (int ss = 0; ss < 2; ++ss)
        #pragma unroll
        for (int t = 0; t < 2; ++t) {
            f32x16 acc;
            #pragma unroll
            for (int j = 0; j < 16; ++j) acc[j] = 0.f;
            #pragma unroll
            for (int m = 0; m < 4; ++m)
                acc = __builtin_amdgcn_mfma_f32_32x32x16_f16(Af[ss][m], Bf[t*4+m], acc, 0, 0, 0);
            #pragma unroll
            for (int q = 0; q < 4; ++q) {
                uint2 wv;
                wv.x = __builtin_bit_cast(unsigned, __builtin_amdgcn_cvt_pkrtz(acc[4*q+0], acc[4*q+1]));
                wv.y = __builtin_bit_cast(unsigned, __builtin_amdgcn_cvt_pkrtz(acc[4*q+2], acc[4*q+3]));
                *(uint2*)(st + (wb ^ lam2((ss << 12) | ((q & 1) << 3) | ((q >> 1) << 13), t))) = wv;
            }
        }
    __syncthreads();
}

template<int L>
__device__ __forceinline__ void apply2(_Float16* st, const _Float16* B,
                                       int lane, int l31, int h, int w) {
    constexpr int GW = find_g0(L);
    half8 Af[4][2];
    const int rb = lam2((h << 3) | (w << 4) | (l31 << 9), 0);
    #pragma unroll
    for (int ss = 0; ss < 4; ++ss)
        #pragma unroll
        for (int m = 0; m < 2; ++m)
            Af[ss][m] = *(const half8*)(st + (rb ^ lam2(ss << 7, m)));
    __syncthreads();
    half8 Bf[2];
    #pragma unroll
    for (int f = 0; f < 2; ++f)
        Bf[f] = *(const half8*)(B + ((L*18 + 16 + f)*64 + lane)*8);
    constexpr int C0 = lam0(ring_F(L, 1), 0, GW);
    constexpr int C1 = lam0(ring_F(L, 2), 0, GW);
    constexpr int C2 = lam0(ring_F(L, 4), 0, GW);
    constexpr int C3 = lam0(ring_F(L, 8), 0, GW);
    constexpr int CP = lam0(0, 1, GW);
    constexpr int CH = lam0(ring_F(L, 1 << 11), 0, GW);
    constexpr int CW0 = lam0(ring_F(L, 1 << 4), 0, GW);
    constexpr int CW1 = lam0(ring_F(L, 1 << 5), 0, GW);
    constexpr int CW2 = lam0(ring_F(L, 1 << 6), 0, GW);
    constexpr int CS0 = lam0(ring_F(L, 1 << 7), 0, GW);
    constexpr int CS1 = lam0(ring_F(L, 1 << 8), 0, GW);
    constexpr int E9  = lam0(ring_F(L, 1 << 9), 0, GW);
    constexpr int E10 = lam0(ring_F(L, 1 << 10), 0, GW);
    constexpr int E12 = lam0(ring_F(L, 1 << 12), 0, GW);
    constexpr int E13 = lam0(ring_F(L, 1 << 13), 0, GW);
    int wb = ((l31 & 1) ? C0 : 0) ^ ((l31 & 2) ? C1 : 0) ^ ((l31 & 4) ? C2 : 0)
           ^ ((l31 & 8) ? C3 : 0) ^ ((l31 & 16) ? CP : 0) ^ (h ? CH : 0)
           ^ ((w & 1) ? CW0 : 0) ^ ((w & 2) ? CW1 : 0) ^ ((w & 4) ? CW2 : 0);
    #pragma unroll
    for (int ss = 0; ss < 4; ++ss) {
        f32x16 acc;
        #pragma unroll
        for (int j = 0; j < 16; ++j) acc[j] = 0.f;
        acc = __builtin_amdgcn_mfma_f32_32x32x16_f16(Af[ss][0], Bf[0], acc, 0, 0, 0);
        acc = __builtin_amdgcn_mfma_f32_32x32x16_f16(Af[ss][1], Bf[1], acc, 0, 0, 0);
        const int ws_ = wb ^ ((ss & 1) ? CS0 : 0) ^ ((ss & 2) ? CS1 : 0);
        #pragma unroll
        for (int r = 0; r < 16; ++r) {
            int wa = ws_ ^ ((r & 1) ? E9 : 0) ^ ((r & 2) ? E10 : 0)
                         ^ ((r & 4) ? E12 : 0) ^ ((r & 8) ? E13 : 0);
            st[wa] = (_Float16)acc[r];
        }
    }
    __syncthreads();
}

template<int L>
__device__ __forceinline__ void do_layer(_Float16* st, const _Float16* B,
                                         int lane, int l31, int h, int w) {
    apply0<L>(st, B, lane, l31, h, w);
    apply1<L>(st, B, lane, l31, h, w);
    apply2<L>(st, B, lane, l31, h, w);
    if constexpr (L < NL - 1) do_layer<L+1>(st, B, lane, l31, h, w);
}

__global__ void __launch_bounds__(NT, 4)
qsim_kernel(const float* __restrict__ x, const _Float16* __restrict__ B,
            float* __restrict__ out)
{
    __shared__ _Float16 st[32768];
    const int tid = threadIdx.x;
    const int lane = tid & 63, wid = tid >> 6;
    const int l31 = lane & 31, h = lane >> 5;
    const float* xb = x + blockIdx.x * NQ;

    // ---- product-state init, written directly in Lam0^GINIT as b128s ----
    {
        float cr = 1.f, ci = 0.f;
        #pragma unroll
        for (int bb = 0; bb < 3; ++bb) {
            float s, c; __sincosf(0.5f * xb[13 - bb], &s, &c);
            if ((wid >> bb) & 1) { float nr = s*ci, ni = -s*cr; cr = nr; ci = ni; }
            else                 { cr *= c; ci *= c; }
        }
        {
            float s, c; __sincosf(0.5f * xb[10], &s, &c);
            if (h) { float nr = s*ci, ni = -s*cr; cr = nr; ci = ni; }
            else   { cr *= c; ci *= c; }
        }
        #pragma unroll
        for (int bb = 0; bb < 5; ++bb) {
            float s, c; __sincosf(0.5f * xb[9 - bb], &s, &c);
            if ((l31 >> bb) & 1) { float nr = s*ci, ni = -s*cr; cr = nr; ci = ni; }
            else                 { cr *= c; ci *= c; }
        }
        float es[3], ec[3];
        #pragma unroll
        for (int bb = 0; bb < 3; ++bb) __sincosf(0.5f * xb[4 - bb], &es[bb], &ec[bb]);
        float s1, c1, s0, c0;
        __sincosf(0.5f * xb[1], &s1, &c1);
        __sincosf(0.5f * xb[0], &s0, &c0);
        const int ib = lam0(wid | (h << 3) | (l31 << 4), 0, GINIT);
        #pragma unroll
        for (int j2 = 0; j2 < 4; ++j2) {
            float dr = cr, di = ci;
            if (j2 & 1) { float nr = s1*di, ni = -s1*dr; dr = nr; di = ni; }
            else        { dr *= c1; di *= c1; }
            if (j2 >> 1) { float nr = s0*di, ni = -s0*dr; dr = nr; di = ni; }
            else         { dr *= c0; di *= c0; }
            half8 R, I;
            #pragma unroll
            for (int e = 0; e < 8; ++e) {
                float rr = dr, ii = di;
                #pragma unroll
                for (int bb = 0; bb < 3; ++bb) {
                    if ((e >> bb) & 1) { float nr = es[bb]*ii, ni = -es[bb]*rr; rr = nr; ii = ni; }
                    else               { rr *= ec[bb]; ii *= ec[bb]; }
                }
                R[e] = (_Float16)rr; I[e] = (_Float16)ii;
            }
            int da = ((j2 & 1) << 12) | ((j2 >> 1) << 13);
            *(half8*)(st + (ib ^ lam0(da, 0, GINIT))) = R;
            *(half8*)(st + (ib ^ lam0(da, 1, GINIT))) = I;
        }
    }
    __syncthreads();

    do_layer<0>(st, B, lane, l31, h, wid);

    // ---- <Z0>: read via the apply0 pattern on Lam0^{G5}; sign = a13 = m0 ----
    {
        constexpr int G5 = find_g0(NL - 1);
        const int rb = lam0(wid | (l31 << 4) | (h << 12), 0, G5);
        float acc = 0.f;
        #pragma unroll
        for (int ss = 0; ss < 2; ++ss)
            #pragma unroll
            for (int m0 = 0; m0 < 2; ++m0) {
                half8 re = *(const half8*)(st + (rb ^ lam0((ss << 3) | (m0 << 13), 0, G5)));
                half8 im = *(const half8*)(st + (rb ^ lam0((ss << 3) | (m0 << 13), 1, G5)));
                float s = 0.f;
                #pragma unroll
                for (int e = 0; e < 8; ++e) {
                    float r = (float)re[e], iv = (float)im[e];
                    s += r*r + iv*iv;
                }
                acc += m0 ? -s : s;
            }
        #pragma unroll
        for (int off = 32; off > 0; off >>= 1) acc += __shfl_down(acc, off, 64);
        __syncthreads();
        float* f = (float*)st;
        if ((tid & 63) == 0) f[tid >> 6] = acc;
        __syncthreads();
        if (tid == 0) {
            float s = 0.f;
            #pragma unroll
            for (int w = 0; w < NT/64; ++w) s += f[w];
            out[blockIdx.x] = s;
        }
    }
}

extern "C" void kernel_launch(void* const* d_in, const int* in_sizes, int n_in,
                              void* d_out, int out_size, void* d_ws, size_t ws_size,
                              hipStream_t stream) {
    const float* x = (const float*)d_in[0];   // (1024, 14) float32
    const float* w = (const float*)d_in[1];   // (6, 14, 3) float32
    float* out = (float*)d_out;               // (1024,) float32
    _Float16* B = (_Float16*)d_ws;            // 6*18*64*8 halfs of B-frags

    prepB_kernel<<<27, 256, 0, stream>>>(w, B);
    qsim_kernel<<<BATCH, NT, 0, stream>>>(x, B, out);
}